// Round 5
// baseline (209.565 us; speedup 1.0000x reference)
//
#include <hip/hip_runtime.h>
#include <hip/hip_bf16.h>
#include <stdint.h>

typedef __bf16 bf16;
typedef __bf16 bf16x8 __attribute__((ext_vector_type(8)));
typedef float floatx4 __attribute__((ext_vector_type(4)));

typedef const __attribute__((address_space(1))) uint32_t glb_u32;
typedef __attribute__((address_space(3))) uint32_t lds_u32;

__device__ __forceinline__ void cp16(void* lds, const void* gp) {
    __builtin_amdgcn_global_load_lds((glb_u32*)gp, (lds_u32*)lds, 16, 0, 0);
}

#define MFMA16(a, b, c) __builtin_amdgcn_mfma_f32_16x16x32_bf16((a), (b), (c), 0, 0, 0)
#define SCALE_ 0.125f

// ---------------------------------------------------------------------------
// K0: fused cvt + prep + xsum.
// blocks [0,4096): fp32->bf16 cvt of x (hi + lo residual), w_qkv, w_out
// blocks [4096,4352): whl[d][k]=bf16_hi(mean_h wq), whl[64+d][k]=bf16_lo
// blocks [4352,4416): xsum[b][c] = sum_n x[b][n][c]  (fp32)
// ---------------------------------------------------------------------------
__global__ __launch_bounds__(256) void k_cvt_prep(
    const float* __restrict__ x, const float* __restrict__ wq,
    const float* __restrict__ wo, bf16* __restrict__ xb,
    bf16* __restrict__ xl, bf16* __restrict__ wqb, bf16* __restrict__ wob,
    bf16* __restrict__ whl, float* __restrict__ xsum) {
    __shared__ float red[4][64];
    if (blockIdx.x < 4096) {
        size_t i8 = ((size_t)blockIdx.x * 256 + threadIdx.x) * 8;
        const float* src; bf16* dst; size_t off; bool isx = false;
        if (i8 < 4194304)      { src = x;  dst = xb;  off = i8; isx = true; }
        else if (i8 < 7340032) { src = wq; dst = wqb; off = i8 - 4194304; }
        else                   { src = wo; dst = wob; off = i8 - 7340032; }
        float4 a = *(const float4*)(src + off);
        float4 b = *(const float4*)(src + off + 4);
        union { bf16 h[8]; uint4 u; } hi, lo;
        hi.h[0] = (bf16)a.x; hi.h[1] = (bf16)a.y; hi.h[2] = (bf16)a.z; hi.h[3] = (bf16)a.w;
        hi.h[4] = (bf16)b.x; hi.h[5] = (bf16)b.y; hi.h[6] = (bf16)b.z; hi.h[7] = (bf16)b.w;
        *(uint4*)(dst + off) = hi.u;
        if (isx) {
            lo.h[0] = (bf16)(a.x - (float)hi.h[0]);
            lo.h[1] = (bf16)(a.y - (float)hi.h[1]);
            lo.h[2] = (bf16)(a.z - (float)hi.h[2]);
            lo.h[3] = (bf16)(a.w - (float)hi.h[3]);
            lo.h[4] = (bf16)(b.x - (float)hi.h[4]);
            lo.h[5] = (bf16)(b.y - (float)hi.h[5]);
            lo.h[6] = (bf16)(b.z - (float)hi.h[6]);
            lo.h[7] = (bf16)(b.w - (float)hi.h[7]);
            *(uint4*)(xl + off) = lo.u;
        }
    } else if (blockIdx.x < 4352) {
        int t = (blockIdx.x - 4096) * 256 + threadIdx.x;   // 0..65535
        int k = t & 1023, d = t >> 10;
        float s = 0.f;
        #pragma unroll
        for (int h = 0; h < 16; ++h) s += wq[(size_t)(h * 64 + d) * 1024 + k];
        s *= (1.f / 16.f);
        bf16 hi = (bf16)s;
        whl[(size_t)d * 1024 + k] = hi;
        whl[(size_t)(64 + d) * 1024 + k] = (bf16)(s - (float)hi);
    } else {
        int j = blockIdx.x - 4352;                 // 0..63
        int b = j >> 4, c0 = (j & 15) << 6;
        int lane = threadIdx.x & 63, q = threadIdx.x >> 6;
        const float* p = x + (size_t)b * 1048576 + (size_t)q * 262144 + c0 + lane;
        float s = 0.f;
        #pragma unroll 8
        for (int n = 0; n < 256; ++n) s += p[(size_t)n * 1024];
        red[q][lane] = s;
        __syncthreads();
        if (threadIdx.x < 64)
            xsum[b * 1024 + c0 + threadIdx.x] =
                red[0][threadIdx.x] + red[1][threadIdx.x] +
                red[2][threadIdx.x] + red[3][threadIdx.x];
    }
}

// ---------------------------------------------------------------------------
// K1a: qm GEMM, split-K x8, 2-phase double-buffered staging.
// grid 512 = 64 m-tiles x 8 k-slices; 64 rows x 64 cols x K=128 per block.
// Partials -> qm8[ks][4096][64] fp32 (aliased over qsel/ksel/VselT slots).
// ---------------------------------------------------------------------------
__global__ __launch_bounds__(256) void k_score_gemm(
    const bf16* __restrict__ xh, const bf16* __restrict__ xl,
    const bf16* __restrict__ whl, float* __restrict__ qm8) {
    __shared__ bf16 Ah[2 * 2048];
    __shared__ bf16 Al[2 * 2048];
    __shared__ bf16 Bs[2 * 4096];
    const int t = threadIdx.x;
    const int lane = t & 63;
    const int w = t >> 6;
    const int m0 = (blockIdx.x >> 3) * 64;
    const int kbase = (blockIdx.x & 7) * 128;
    const int srow = t >> 2;           // 0..63
    const int scol = (t & 3) * 8;
    const int fr = lane & 15;
    const int kc = (lane >> 4) * 8;

#define STAGE_SC(bi, k0) do { \
    bf16* Ahd_ = Ah + (bi) * 2048; \
    bf16* Ald_ = Al + (bi) * 2048; \
    bf16* Bd_  = Bs + (bi) * 4096; \
    cp16(Ahd_ + t * 8,       xh + (size_t)(m0 + srow) * 1024 + (k0) + scol); \
    cp16(Ald_ + t * 8,       xl + (size_t)(m0 + srow) * 1024 + (k0) + scol); \
    cp16(Bd_ + t * 8,        whl + (size_t)srow * 1024 + (k0) + scol); \
    cp16(Bd_ + t * 8 + 2048, whl + (size_t)(srow + 64) * 1024 + (k0) + scol); \
} while (0)

    floatx4 zero4 = {0.f, 0.f, 0.f, 0.f};
    floatx4 acc[4] = {zero4, zero4, zero4, zero4};

    STAGE_SC(0, kbase);
    int cur = 0;
    for (int it = 0; it < 4; ++it) {
        if (it < 3) {
            STAGE_SC(cur ^ 1, kbase + (it + 1) * 32);
            asm volatile("s_waitcnt vmcnt(4)" ::: "memory");
        } else {
            asm volatile("s_waitcnt vmcnt(0)" ::: "memory");
        }
        __builtin_amdgcn_s_barrier();
        const bf16* Ahc = Ah + cur * 2048;
        const bf16* Alc = Al + cur * 2048;
        const bf16* Bc  = Bs + cur * 4096;
        bf16x8 ah, al, bh[4], bl[4];
        ah = *(const bf16x8*)&Ahc[(w * 16 + fr) * 32 + kc];
        al = *(const bf16x8*)&Alc[(w * 16 + fr) * 32 + kc];
        #pragma unroll
        for (int ni = 0; ni < 4; ++ni) {
            bh[ni] = *(const bf16x8*)&Bc[(ni * 16 + fr) * 32 + kc];
            bl[ni] = *(const bf16x8*)&Bc[(64 + ni * 16 + fr) * 32 + kc];
        }
        #pragma unroll
        for (int ni = 0; ni < 4; ++ni) {
            acc[ni] = MFMA16(ah, bh[ni], acc[ni]);
            acc[ni] = MFMA16(ah, bl[ni], acc[ni]);
            acc[ni] = MFMA16(al, bh[ni], acc[ni]);
        }
        __builtin_amdgcn_s_barrier();
        cur ^= 1;
    }
#undef STAGE_SC

    const int rowb = (lane >> 4) * 4;
    const size_t kofs = (size_t)(blockIdx.x & 7) * 4096;
    #pragma unroll
    for (int ni = 0; ni < 4; ++ni)
        #pragma unroll
        for (int r = 0; r < 4; ++r)
            qm8[(kofs + m0 + w * 16 + rowb + r) * 64 + ni * 16 + fr] = acc[ni][r];
}

// ---------------------------------------------------------------------------
// K1b: sum 8 partials -> LN -> GELU -> score. Wave = 1 row, 1024 blocks.
// ---------------------------------------------------------------------------
__global__ __launch_bounds__(256) void k_score_tail(
    const float* __restrict__ qm8, const float* __restrict__ lng,
    const float* __restrict__ lnb, const float* __restrict__ w1f,
    const float* __restrict__ b1f, const float* __restrict__ w2f,
    const float* __restrict__ b2f, float* __restrict__ scores) {
    const int w = threadIdx.x >> 6, lane = threadIdx.x & 63;
    const int r = blockIdx.x * 4 + w;
    __shared__ float Hs[4][64];
    __shared__ float hh[4][16];

    float qm = 0.f;
    #pragma unroll
    for (int ks = 0; ks < 8; ++ks)
        qm += qm8[((size_t)ks * 4096 + r) * 64 + lane];
    float s = qm;
    #pragma unroll
    for (int off = 32; off > 0; off >>= 1) s += __shfl_xor(s, off);
    float mu = s * (1.f / 64.f);
    float dx = qm - mu;
    float v2 = dx * dx;
    #pragma unroll
    for (int off = 32; off > 0; off >>= 1) v2 += __shfl_xor(v2, off);
    float var = v2 * (1.f / 64.f);
    float H = dx * (1.0f / sqrtf(var + 1e-5f)) * lng[lane] + lnb[lane];
    Hs[w][lane] = H;
    if (lane < 16) {
        float a = b1f[lane];
        #pragma unroll
        for (int d = 0; d < 64; ++d) a += Hs[w][d] * w1f[lane * 64 + d];
        hh[w][lane] = 0.5f * a * (1.0f + erff(a * 0.70710678118654752f));
    }
    if (lane == 0) {
        float sc = b2f[0];
        #pragma unroll
        for (int p = 0; p < 16; ++p) sc += hh[w][p] * w2f[p];
        scores[r] = sc;
    }
}

// ---------------------------------------------------------------------------
// K2: top-256 radix select; emits full gate, ascending index list, compact gate.
// ---------------------------------------------------------------------------
__global__ __launch_bounds__(256) void k_topk(const float* __restrict__ scores,
                                              float* __restrict__ gate,
                                              int* __restrict__ idx,
                                              float* __restrict__ gsel) {
    const int w = threadIdx.x >> 6, lane = threadIdx.x & 63;   // w = batch
    const float* sc = scores + w * 1024;
    float s[16];
    uint32_t key[16];
    #pragma unroll
    for (int i = 0; i < 16; ++i) {
        s[i] = sc[lane * 16 + i];
        uint32_t u = __float_as_uint(s[i]);
        key[i] = (u >> 31) ? ~u : (u | 0x80000000u);
    }
    uint32_t prefix = 0;
    for (int bit = 31; bit >= 0; --bit) {
        uint32_t cand = prefix | (1u << bit);
        int c = 0;
        #pragma unroll
        for (int i = 0; i < 16; ++i) c += (key[i] >= cand);
        #pragma unroll
        for (int off = 1; off < 64; off <<= 1) c += __shfl_xor(c, off);
        if (c >= 256) prefix = cand;
    }
    int cg = 0, eq = 0;
    #pragma unroll
    for (int i = 0; i < 16; ++i) { cg += (key[i] > prefix); eq += (key[i] == prefix); }
    #pragma unroll
    for (int off = 1; off < 64; off <<= 1) cg += __shfl_xor(cg, off);
    const int quota = 256 - cg;
    int xs = eq;
    #pragma unroll
    for (int off = 1; off < 64; off <<= 1) {
        int y = __shfl_up(xs, off);
        if (lane >= off) xs += y;
    }
    int run = xs - eq;
    bool selv[16];
    int cnt = 0;
    #pragma unroll
    for (int i = 0; i < 16; ++i) {
        bool sel = key[i] > prefix;
        if (key[i] == prefix) { sel = (run < quota); run++; }
        selv[i] = sel;
        cnt += sel ? 1 : 0;
        gate[w * 1024 + lane * 16 + i] = sel ? 1.0f / (1.0f + expf(-s[i])) : 0.0f;
    }
    int xc = cnt;
    #pragma unroll
    for (int off = 1; off < 64; off <<= 1) {
        int y = __shfl_up(xc, off);
        if (lane >= off) xc += y;
    }
    int pos = xc - cnt;
    #pragma unroll
    for (int i = 0; i < 16; ++i) {
        if (selv[i]) {
            idx[w * 256 + pos]  = lane * 16 + i;
            gsel[w * 256 + pos] = 1.0f / (1.0f + expf(-s[i]));
            pos++;
        }
    }
}

// ---------------------------------------------------------------------------
// K3: sparse QKV on the 1024 gathered rows, cols [0,3072) over wq|wk|wv.
// 2-phase double-buffered staging. q -> qsel, k -> ksel, v -> VselT.
// blocks [0,192): GEMM tiles. blocks [192,208): meanVbuf[b][k2]=(xsum.wv)/1024.
// ---------------------------------------------------------------------------
__global__ __launch_bounds__(256) void k_qkv_sel(
    const bf16* __restrict__ xb, const bf16* __restrict__ wqb,
    const int* __restrict__ idx, bf16* __restrict__ qsel,
    bf16* __restrict__ ksel, bf16* __restrict__ VselT,
    const float* __restrict__ xsum, float* __restrict__ meanVbuf) {
    __shared__ bf16 As[2 * 4096];
    __shared__ bf16 Bs[2 * 4096];
    __shared__ float xsS[1024];
    const int t = threadIdx.x;

    if (blockIdx.x >= 192) {
        const int j = blockIdx.x - 192, b = j >> 2, kq = j & 3;
        for (int k = t; k < 1024; k += 256) xsS[k] = xsum[b * 1024 + k];
        __syncthreads();
        const int k2 = kq * 256 + t;
        const bf16* wr = wqb + (size_t)(2048 + k2) * 1024;
        float s = 0.f;
        for (int k = 0; k < 1024; k += 8) {
            bf16x8 v = *(const bf16x8*)(wr + k);
            #pragma unroll
            for (int jj = 0; jj < 8; ++jj) s += (float)v[jj] * xsS[k + jj];
        }
        meanVbuf[b * 1024 + k2] = s * (1.f / 1024.f);
        return;
    }

    const int lane = t & 63;
    const int w = t >> 6;
    const int srow = t >> 2;
    const int scol = (t & 3) * 8;
    const int wm = (w & 1) * 64;
    const int wn = (w >> 1) * 64;
    const int fr = lane & 15;
    const int kc = (lane >> 4) * 8;

    const int bid = blockIdx.x;
    const int n0 = (bid % 24) * 128;   // [0,3072) over wq|wk|wv
    const int m0 = (bid / 24) * 128;   // compact rows [0,1024)
    const bf16* Bsrc = wqb + (size_t)n0 * 1024;
    const int mg1 = m0 + srow, mg2 = mg1 + 64;
    const int tok1 = idx[(mg1 >> 8) * 256 + (mg1 & 255)];
    const int tok2 = idx[(mg2 >> 8) * 256 + (mg2 & 255)];
    const size_t abase1 = ((size_t)(mg1 >> 8) * 1024 + tok1) * 1024;
    const size_t abase2 = ((size_t)(mg2 >> 8) * 1024 + tok2) * 1024;

#define STAGE_QKV(bi, k0) do { \
    bf16* Ad_ = As + (bi) * 4096; \
    bf16* Bd_ = Bs + (bi) * 4096; \
    cp16(Ad_ + t * 8,        xb + abase1 + (k0) + scol); \
    cp16(Ad_ + t * 8 + 2048, xb + abase2 + (k0) + scol); \
    cp16(Bd_ + t * 8,        Bsrc + (size_t)srow * 1024 + (k0) + scol); \
    cp16(Bd_ + t * 8 + 2048, Bsrc + (size_t)(srow + 64) * 1024 + (k0) + scol); \
} while (0)

    floatx4 zero4 = {0.f, 0.f, 0.f, 0.f};
    floatx4 acc[4][4];
    #pragma unroll
    for (int i = 0; i < 4; ++i)
        #pragma unroll
        for (int j = 0; j < 4; ++j) acc[i][j] = zero4;

    STAGE_QKV(0, 0);
    int cur = 0;
    for (int it = 0; it < 32; ++it) {
        if (it < 31) {
            STAGE_QKV(cur ^ 1, (it + 1) * 32);
            asm volatile("s_waitcnt vmcnt(4)" ::: "memory");
        } else {
            asm volatile("s_waitcnt vmcnt(0)" ::: "memory");
        }
        __builtin_amdgcn_s_barrier();
        const bf16* Ac = As + cur * 4096;
        const bf16* Bc = Bs + cur * 4096;
        bf16x8 a[4], b[4];
        #pragma unroll
        for (int mi = 0; mi < 4; ++mi)
            a[mi] = *(const bf16x8*)&Ac[(wm + mi * 16 + fr) * 32 + kc];
        #pragma unroll
        for (int ni = 0; ni < 4; ++ni)
            b[ni] = *(const bf16x8*)&Bc[(wn + ni * 16 + fr) * 32 + kc];
        #pragma unroll
        for (int mi = 0; mi < 4; ++mi)
            #pragma unroll
            for (int ni = 0; ni < 4; ++ni)
                acc[mi][ni] = MFMA16(a[mi], b[ni], acc[mi][ni]);
        __builtin_amdgcn_s_barrier();
        cur ^= 1;
    }
#undef STAGE_QKV

    const int rowb = (lane >> 4) * 4;
    #pragma unroll
    for (int ni = 0; ni < 4; ++ni) {
        const int n_base = n0 + wn + ni * 16;
        const int region = n_base >> 10;   // 0=q 1=k 2=v
        const int nn = n_base & 1023;
        const int h = nn >> 6;
        const int dd = (nn & 63) + fr;
        if (region < 2) {
            #pragma unroll
            for (int mi = 0; mi < 4; ++mi)
                #pragma unroll
                for (int r = 0; r < 4; ++r) {
                    const int mg = m0 + wm + mi * 16 + rowb + r;  // compact row
                    const bf16 v = (bf16)acc[mi][ni][r];
                    if (region == 0) {
                        qsel[(size_t)mg * 1024 + h * 64 + dd] = v;
                    } else {
                        const int b = mg >> 8, s = mg & 255;
                        ksel[(((size_t)(b * 16 + h)) * 256 + s) * 64 + dd] = v;
                    }
                }
        } else {
            #pragma unroll
            for (int mi = 0; mi < 4; ++mi) {
                const int mgb = m0 + wm + mi * 16 + rowb;   // multiple of 4
                const int b = mgb >> 8, s0 = mgb & 255;
                union { bf16 h4[4]; uint2 u; } pk;
                #pragma unroll
                for (int r = 0; r < 4; ++r) pk.h4[r] = (bf16)acc[mi][ni][r];
                *(uint2*)&VselT[(((size_t)(b * 16 + h)) * 64 + dd) * 256 + s0] = pk.u;
            }
        }
    }
}

// ---------------------------------------------------------------------------
// K4: gated attention (256 blocks, bh x qt) with fused in-block SumVuns
//     (= meanVbuf*1024 - sum_s VselT), + 16 ubase blocks (meanV @ wo + b_out).
// ---------------------------------------------------------------------------
__global__ __launch_bounds__(256) void k_attn(
    bf16* __restrict__ qsel, const bf16* __restrict__ Ksel,
    const bf16* __restrict__ VselT, const float* __restrict__ gsel,
    const float* __restrict__ meanVbuf, const bf16* __restrict__ wob,
    const float* __restrict__ b_out, float* __restrict__ ubase) {
    __shared__ bf16 Qs[64 * 72];
    __shared__ bf16 Ks[64 * 72];
    __shared__ bf16 Vs[64 * 72];
    __shared__ bf16 Ps[4][16 * 72];
    __shared__ float redS[4][64];
    __shared__ float SumV[64];
    __shared__ float mvS[1024];
    const int t = threadIdx.x;

    if (blockIdx.x >= 256) {
        const int j = blockIdx.x - 256, bb = j >> 2, nq = j & 3;
        for (int k = t; k < 1024; k += 256) mvS[k] = meanVbuf[bb * 1024 + k];
        __syncthreads();
        const int n = nq * 256 + t;
        const bf16* wr = wob + (size_t)n * 1024;
        float s = b_out[n];
        for (int k = 0; k < 1024; k += 8) {
            bf16x8 v = *(const bf16x8*)(wr + k);
            #pragma unroll
            for (int jj = 0; jj < 8; ++jj) s += (float)v[jj] * mvS[k + jj];
        }
        ubase[bb * 1024 + n] = s;
        return;
    }

    const int bh = blockIdx.x >> 2;   // 0..63
    const int qt = blockIdx.x & 3;    // 0..3
    const int b = bh >> 4, h = bh & 15;
    const int w = t >> 6, lane = t & 63;
    const int m0 = qt * 64;      // compact row within batch
    const bf16* kb = Ksel + (size_t)bh * 16384;
    const bf16* vb = VselT + (size_t)bh * 16384;

    #pragma unroll
    for (int c = 0; c < 2; ++c) {
        int idx2 = t + 256 * c, row = idx2 >> 3, c8 = (idx2 & 7) * 8;
        *(uint4*)&Qs[row * 72 + c8] =
            *(const uint4*)&qsel[(size_t)(b * 256 + m0 + row) * 1024 + h * 64 + c8];
    }
    // sSel partials: thread (d = t&63, part = t>>6) sums 64 s of VselT[bh][d][:]
    {
        const int dd_ = t & 63, pp_ = t >> 6;
        const bf16* vr = vb + (size_t)dd_ * 256 + pp_ * 64;
        float ss = 0.f;
        #pragma unroll
        for (int k = 0; k < 64; k += 8) {
            bf16x8 v = *(const bf16x8*)(vr + k);
            #pragma unroll
            for (int jj = 0; jj < 8; ++jj) ss += (float)v[jj];
        }
        redS[pp_][dd_] = ss;
    }
    const int fr = lane & 15;
    const int kq = lane >> 4;
    const int rowb = kq * 4;
    __syncthreads();
    if (t < 64)
        SumV[t] = meanVbuf[b * 1024 + h * 64 + t] * 1024.f -
                  (redS[0][t] + redS[1][t] + redS[2][t] + redS[3][t]);
    bf16x8 aq[2];
    aq[0] = *(const bf16x8*)&Qs[(w * 16 + fr) * 72 + kq * 8];
    aq[1] = *(const bf16x8*)&Qs[(w * 16 + fr) * 72 + 32 + kq * 8];

    float gq[4];
    #pragma unroll
    for (int r = 0; r < 4; ++r)
        gq[r] = gsel[b * 256 + m0 + w * 16 + rowb + r] * SCALE_;

    float mrow[4] = {0.f, 0.f, 0.f, 0.f};
    float lrow[4] = {0.f, 0.f, 0.f, 0.f};
    floatx4 zero4 = {0.f, 0.f, 0.f, 0.f};
    floatx4 Of[4] = {zero4, zero4, zero4, zero4};

    for (int jt = 0; jt < 4; ++jt) {
        const int j0 = jt * 64;
        __syncthreads();
        #pragma unroll
        for (int c = 0; c < 2; ++c) {
            int idx2 = t + 256 * c, row = idx2 >> 3, c8 = (idx2 & 7) * 8;
            *(uint4*)&Ks[row * 72 + c8] = *(const uint4*)&kb[(size_t)(j0 + row) * 64 + c8];
            *(uint4*)&Vs[row * 72 + c8] = *(const uint4*)&vb[(size_t)row * 256 + j0 + c8];
        }
        __syncthreads();

        floatx4 S[4] = {zero4, zero4, zero4, zero4};
        #pragma unroll
        for (int ks = 0; ks < 2; ++ks) {
            #pragma unroll
            for (int ni = 0; ni < 4; ++ni) {
                bf16x8 bfr = *(const bf16x8*)&Ks[(ni * 16 + fr) * 72 + ks * 32 + kq * 8];
                S[ni] = MFMA16(aq[ks], bfr, S[ni]);
            }
        }
        float gk[4];
        #pragma unroll
        for (int ni = 0; ni < 4; ++ni) gk[ni] = gsel[b * 256 + j0 + ni * 16 + fr];

        float p[4][4], rmax[4] = {0.f, 0.f, 0.f, 0.f};
        #pragma unroll
        for (int ni = 0; ni < 4; ++ni)
            #pragma unroll
            for (int r = 0; r < 4; ++r) {
                float sv = S[ni][r] * (gq[r] * gk[ni]);
                p[ni][r] = sv;
                rmax[r] = fmaxf(rmax[r], sv);
            }
        #pragma unroll
        for (int r = 0; r < 4; ++r) {
            #pragma unroll
            for (int off = 1; off < 16; off <<= 1)
                rmax[r] = fmaxf(rmax[r], __shfl_xor(rmax[r], off));
        }
        float alpha[4], rsum[4] = {0.f, 0.f, 0.f, 0.f};
        #pragma unroll
        for (int r = 0; r < 4; ++r) {
            float mn = fmaxf(mrow[r], rmax[r]);
            alpha[r] = __expf(mrow[r] - mn);
            mrow[r] = mn;
        }
        #pragma unroll
        for (int ni = 0; ni < 4; ++ni)
            #pragma unroll
            for (int r = 0; r < 4; ++r) {
                float pv = __expf(p[ni][r] - mrow[r]);
                p[ni][r] = pv;
                rsum[r] += pv;
            }
        #pragma unroll
        for (int r = 0; r < 4; ++r) {
            #pragma unroll
            for (int off = 1; off < 16; off <<= 1) rsum[r] += __shfl_xor(rsum[r], off);
            lrow[r] = lrow[r] * alpha[r] + rsum[r];
        }
        #pragma unroll
        for (int nd = 0; nd < 4; ++nd)
            #pragma unroll
            for (int r = 0; r < 4; ++r) Of[nd][r] *= alpha[r];

        #pragma unroll
        for (int ni = 0; ni < 4; ++ni)
            #pragma unroll
            for (int r = 0; r < 4; ++r)
                Ps[w][(rowb + r) * 72 + ni * 16 + fr] = (bf16)p[ni][r];

        #pragma unroll
        for (int ks = 0; ks < 2; ++ks) {
            bf16x8 ap = *(const bf16x8*)&Ps[w][fr * 72 + ks * 32 + kq * 8];
            #pragma unroll
            for (int nd = 0; nd < 4; ++nd) {
                bf16x8 bv = *(const bf16x8*)&Vs[(nd * 16 + fr) * 72 + ks * 32 + kq * 8];
                Of[nd] = MFMA16(ap, bv, Of[nd]);
            }
        }
    }

    #pragma unroll
    for (int nd = 0; nd < 4; ++nd)
        #pragma unroll
        for (int r = 0; r < 4; ++r) {
            float em = __expf(-mrow[r]);
            float num = Of[nd][r] + em * SumV[nd * 16 + fr];
            float den = lrow[r] + 768.0f * em;
            qsel[(size_t)(b * 256 + m0 + w * 16 + rowb + r) * 1024 +
                 h * 64 + nd * 16 + fr] = (bf16)(num / den);
        }
}

// ---------------------------------------------------------------------------
// K5: out GEMM on compact A (1024 selected rows), 2-phase dbuf staging,
//     scatter to d_out, + fused fill blocks broadcasting ubase[b].
// blocks [0,64): GEMM tiles (8n x 8m). blocks [64,1088): fill, 4 tokens each.
// ---------------------------------------------------------------------------
__global__ __launch_bounds__(256) void k_out_sel(
    const bf16* __restrict__ A, const bf16* __restrict__ wob,
    const float* __restrict__ b_out, const int* __restrict__ idx,
    const float* __restrict__ ubase, const float* __restrict__ gate,
    float* __restrict__ out) {
    __shared__ bf16 As[2 * 4096];
    __shared__ bf16 Bs[2 * 4096];
    const int t = threadIdx.x;
    const int gb = blockIdx.x;

    if (gb >= 64) {
        const int fb = gb - 64;          // 0..1023
        const int c = t * 4;
        #pragma unroll
        for (int r = 0; r < 4; ++r) {
            const int tokg = fb * 4 + r;
            if (gate[tokg] > 0.f) continue;
            const int b = tokg >> 10;
            *(float4*)(out + (size_t)tokg * 1024 + c) =
                *(const float4*)(ubase + b * 1024 + c);
        }
        return;
    }

    const int lane = t & 63;
    const int w = t >> 6;
    const int n0 = (gb & 7) * 128;
    const int m0 = (gb >> 3) * 128;
    const bf16* Bsrc = wob + (size_t)n0 * 1024;

    const int srow = t >> 2;
    const int scol = (t & 3) * 8;
    const int wm = (w & 1) * 64;
    const int wn = (w >> 1) * 64;
    const int fr = lane & 15;
    const int kc = (lane >> 4) * 8;

#define STAGE_OUT(bi, k0) do { \
    bf16* Ad_ = As + (bi) * 4096; \
    bf16* Bd_ = Bs + (bi) * 4096; \
    cp16(Ad_ + t * 8,        A + (size_t)(m0 + srow) * 1024 + (k0) + scol); \
    cp16(Ad_ + t * 8 + 2048, A + (size_t)(m0 + srow + 64) * 1024 + (k0) + scol); \
    cp16(Bd_ + t * 8,        Bsrc + (size_t)srow * 1024 + (k0) + scol); \
    cp16(Bd_ + t * 8 + 2048, Bsrc + (size_t)(srow + 64) * 1024 + (k0) + scol); \
} while (0)

    floatx4 zero4 = {0.f, 0.f, 0.f, 0.f};
    floatx4 acc[4][4];
    #pragma unroll
    for (int i = 0; i < 4; ++i)
        #pragma unroll
        for (int j = 0; j < 4; ++j) acc[i][j] = zero4;

    STAGE_OUT(0, 0);
    int cur = 0;
    for (int it = 0; it < 32; ++it) {
        if (it < 31) {
            STAGE_OUT(cur ^ 1, (it + 1) * 32);
            asm volatile("s_waitcnt vmcnt(4)" ::: "memory");
        } else {
            asm volatile("s_waitcnt vmcnt(0)" ::: "memory");
        }
        __builtin_amdgcn_s_barrier();
        const bf16* Ac = As + cur * 4096;
        const bf16* Bc = Bs + cur * 4096;
        bf16x8 a[4], b[4];
        #pragma unroll
        for (int mi = 0; mi < 4; ++mi)
            a[mi] = *(const bf16x8*)&Ac[(wm + mi * 16 + fr) * 32 + kc];
        #pragma unroll
        for (int ni = 0; ni < 4; ++ni)
            b[ni] = *(const bf16x8*)&Bc[(wn + ni * 16 + fr) * 32 + kc];
        #pragma unroll
        for (int mi = 0; mi < 4; ++mi)
            #pragma unroll
            for (int ni = 0; ni < 4; ++ni)
                acc[mi][ni] = MFMA16(a[mi], b[ni], acc[mi][ni]);
        __builtin_amdgcn_s_barrier();
        cur ^= 1;
    }
#undef STAGE_OUT

    const int rowb = (lane >> 4) * 4;
    #pragma unroll
    for (int ni = 0; ni < 4; ++ni) {
        const int ng = n0 + wn + ni * 16 + fr;
        const float bias = b_out[ng];
        #pragma unroll
        for (int mi = 0; mi < 4; ++mi)
            #pragma unroll
            for (int r = 0; r < 4; ++r) {
                const int mg = m0 + wm + mi * 16 + rowb + r;   // < 1024
                const float val = acc[mi][ni][r] + bias;
                const int bb = mg >> 8, ss = mg & 255;
                const int tok = idx[bb * 256 + ss];
                out[((size_t)bb * 1024 + tok) * 1024 + ng] = val;
            }
    }
}

// ---------------------------------------------------------------------------
extern "C" void kernel_launch(void* const* d_in, const int* in_sizes, int n_in,
                              void* d_out, int out_size, void* d_ws, size_t ws_size,
                              hipStream_t stream) {
    const float* x     = (const float*)d_in[0];
    const float* w_qkv = (const float*)d_in[1];
    const float* w_out = (const float*)d_in[2];
    const float* b_out = (const float*)d_in[3];
    const float* ln_g  = (const float*)d_in[4];
    const float* ln_b  = (const float*)d_in[5];
    const float* w1    = (const float*)d_in[6];
    const float* b1    = (const float*)d_in[7];
    const float* w2    = (const float*)d_in[8];
    const float* b2    = (const float*)d_in[9];
    float* out = (float*)d_out;

    char* ws = (char*)d_ws;
    bf16*  qsel  = (bf16*)(ws);                  // 4 MB slot (1024x1024 bf16 used)
    bf16*  ksel  = (bf16*)(ws + 4194304);        // 2 MB
    bf16*  VselT = (bf16*)(ws + 6291456);        // 2 MB
    float* qm8   = (float*)(ws);                 // 8 MB, aliases qsel|ksel|VselT
                                                 // (consumed by k_score_tail BEFORE
                                                 //  k_qkv_sel writes those slots)
    float* xsum  = (float*)(ws + 8388608);       // 16 KB (4 x 1024 fp32)
    bf16*  xb    = (bf16*)(ws + 16777216);       // 8 MB
    bf16*  wqb   = (bf16*)(ws + 25165824);       // 6 MB
    bf16*  wob   = (bf16*)(ws + 31457280);       // 2 MB
    int*   idx      = (int*)(ws + 33554432);     // 4 KB
    float* gsel     = (float*)(ws + 33558528);   // 4 KB
    float* scores   = (float*)(ws + 33562624);   // 16 KB
    float* gate     = (float*)(ws + 33579008);   // 16 KB
    float* meanVbuf = (float*)(ws + 33595392);   // 16 KB
    float* ubase    = (float*)(ws + 33611776);   // 16 KB
    bf16*  whl      = (bf16*)(ws + 33685504);    // 256 KB (wh|wl rows)
    bf16*  xlbuf    = (bf16*)(ws + 35651584);    // 8 MB (x bf16 residual)

    k_cvt_prep<<<4416, 256, 0, stream>>>(x, w_qkv, w_out, xb, xlbuf, wqb, wob, whl, xsum);
    k_score_gemm<<<512, 256, 0, stream>>>(xb, xlbuf, whl, qm8);
    k_score_tail<<<1024, 256, 0, stream>>>(qm8, ln_g, ln_b, w1, b1, w2, b2, scores);
    k_topk<<<1, 256, 0, stream>>>(scores, gate, idx, gsel);
    k_qkv_sel<<<208, 256, 0, stream>>>(xb, wqb, idx, qsel, ksel, VselT, xsum, meanVbuf);
    k_attn<<<272, 256, 0, stream>>>(qsel, ksel, VselT, gsel, meanVbuf, wob, b_out, ubase);
    k_out_sel<<<1088, 256, 0, stream>>>(qsel, wob, b_out, idx, ubase, gate, out);
}

// Round 6
// 198.108 us; speedup vs baseline: 1.0578x; 1.0578x over previous
//
#include <hip/hip_runtime.h>
#include <hip/hip_bf16.h>
#include <stdint.h>

typedef __bf16 bf16;
typedef __bf16 bf16x8 __attribute__((ext_vector_type(8)));
typedef float floatx4 __attribute__((ext_vector_type(4)));

typedef const __attribute__((address_space(1))) uint32_t glb_u32;
typedef __attribute__((address_space(3))) uint32_t lds_u32;

__device__ __forceinline__ void cp16(void* lds, const void* gp) {
    __builtin_amdgcn_global_load_lds((glb_u32*)gp, (lds_u32*)lds, 16, 0, 0);
}

#define MFMA16(a, b, c) __builtin_amdgcn_mfma_f32_16x16x32_bf16((a), (b), (c), 0, 0, 0)
#define SCALE_ 0.125f

// ---------------------------------------------------------------------------
// K0: fused cvt + prep + xsum.
// blocks [0,4096): fp32->bf16 cvt of x (hi + lo residual), w_qkv, w_out
// blocks [4096,4352): whl[d][k]=bf16_hi(mean_h wq), whl[64+d][k]=bf16_lo
// blocks [4352,4416): xsum[b][c] = sum_n x[b][n][c]  (fp32)
// ---------------------------------------------------------------------------
__global__ __launch_bounds__(256) void k_cvt_prep(
    const float* __restrict__ x, const float* __restrict__ wq,
    const float* __restrict__ wo, bf16* __restrict__ xb,
    bf16* __restrict__ xl, bf16* __restrict__ wqb, bf16* __restrict__ wob,
    bf16* __restrict__ whl, float* __restrict__ xsum) {
    __shared__ float red[4][64];
    if (blockIdx.x < 4096) {
        size_t i8 = ((size_t)blockIdx.x * 256 + threadIdx.x) * 8;
        const float* src; bf16* dst; size_t off; bool isx = false;
        if (i8 < 4194304)      { src = x;  dst = xb;  off = i8; isx = true; }
        else if (i8 < 7340032) { src = wq; dst = wqb; off = i8 - 4194304; }
        else                   { src = wo; dst = wob; off = i8 - 7340032; }
        float4 a = *(const float4*)(src + off);
        float4 b = *(const float4*)(src + off + 4);
        union { bf16 h[8]; uint4 u; } hi, lo;
        hi.h[0] = (bf16)a.x; hi.h[1] = (bf16)a.y; hi.h[2] = (bf16)a.z; hi.h[3] = (bf16)a.w;
        hi.h[4] = (bf16)b.x; hi.h[5] = (bf16)b.y; hi.h[6] = (bf16)b.z; hi.h[7] = (bf16)b.w;
        *(uint4*)(dst + off) = hi.u;
        if (isx) {
            lo.h[0] = (bf16)(a.x - (float)hi.h[0]);
            lo.h[1] = (bf16)(a.y - (float)hi.h[1]);
            lo.h[2] = (bf16)(a.z - (float)hi.h[2]);
            lo.h[3] = (bf16)(a.w - (float)hi.h[3]);
            lo.h[4] = (bf16)(b.x - (float)hi.h[4]);
            lo.h[5] = (bf16)(b.y - (float)hi.h[5]);
            lo.h[6] = (bf16)(b.z - (float)hi.h[6]);
            lo.h[7] = (bf16)(b.w - (float)hi.h[7]);
            *(uint4*)(xl + off) = lo.u;
        }
    } else if (blockIdx.x < 4352) {
        int t = (blockIdx.x - 4096) * 256 + threadIdx.x;   // 0..65535
        int k = t & 1023, d = t >> 10;
        float s = 0.f;
        #pragma unroll
        for (int h = 0; h < 16; ++h) s += wq[(size_t)(h * 64 + d) * 1024 + k];
        s *= (1.f / 16.f);
        bf16 hi = (bf16)s;
        whl[(size_t)d * 1024 + k] = hi;
        whl[(size_t)(64 + d) * 1024 + k] = (bf16)(s - (float)hi);
    } else {
        int j = blockIdx.x - 4352;                 // 0..63
        int b = j >> 4, c0 = (j & 15) << 6;
        int lane = threadIdx.x & 63, q = threadIdx.x >> 6;
        const float* p = x + (size_t)b * 1048576 + (size_t)q * 262144 + c0 + lane;
        float s = 0.f;
        #pragma unroll 8
        for (int n = 0; n < 256; ++n) s += p[(size_t)n * 1024];
        red[q][lane] = s;
        __syncthreads();
        if (threadIdx.x < 64)
            xsum[b * 1024 + c0 + threadIdx.x] =
                red[0][threadIdx.x] + red[1][threadIdx.x] +
                red[2][threadIdx.x] + red[3][threadIdx.x];
    }
}

// ---------------------------------------------------------------------------
// K1a: qm GEMM, split-K x8 (round-4 proven form). grid 512 = 64 m x 8 k.
// Partials -> qm8[ks][4096][64] fp32 (aliased over qsel/ksel/VselT slots).
// ---------------------------------------------------------------------------
__global__ __launch_bounds__(256) void k_score_gemm(
    const bf16* __restrict__ xh, const bf16* __restrict__ xl,
    const bf16* __restrict__ whl, float* __restrict__ qm8) {
    __shared__ bf16 Ah[64 * 32];
    __shared__ bf16 Al[64 * 32];
    __shared__ bf16 Bs[128 * 32];
    const int t = threadIdx.x;
    const int lane = t & 63;
    const int w = t >> 6;
    const int m0 = (blockIdx.x >> 3) * 64;
    const int kbase = (blockIdx.x & 7) * 128;
    const int srow = t >> 2;           // 0..63
    const int scol = (t & 3) * 8;
    const int fr = lane & 15;
    const int kc = (lane >> 4) * 8;

    floatx4 zero4 = {0.f, 0.f, 0.f, 0.f};
    floatx4 acc[4] = {zero4, zero4, zero4, zero4};

    for (int k0 = kbase; k0 < kbase + 128; k0 += 32) {
        __syncthreads();
        cp16(Ah + t * 8,        xh + (size_t)(m0 + srow) * 1024 + k0 + scol);
        cp16(Al + t * 8,        xl + (size_t)(m0 + srow) * 1024 + k0 + scol);
        cp16(Bs + t * 8,        whl + (size_t)srow * 1024 + k0 + scol);
        cp16(Bs + t * 8 + 2048, whl + (size_t)(srow + 64) * 1024 + k0 + scol);
        __syncthreads();
        bf16x8 ah, al, bh[4], bl[4];
        ah = *(const bf16x8*)&Ah[(w * 16 + fr) * 32 + kc];
        al = *(const bf16x8*)&Al[(w * 16 + fr) * 32 + kc];
        #pragma unroll
        for (int ni = 0; ni < 4; ++ni) {
            bh[ni] = *(const bf16x8*)&Bs[(ni * 16 + fr) * 32 + kc];
            bl[ni] = *(const bf16x8*)&Bs[(64 + ni * 16 + fr) * 32 + kc];
        }
        #pragma unroll
        for (int ni = 0; ni < 4; ++ni) {
            acc[ni] = MFMA16(ah, bh[ni], acc[ni]);
            acc[ni] = MFMA16(ah, bl[ni], acc[ni]);
            acc[ni] = MFMA16(al, bh[ni], acc[ni]);
        }
    }

    const int rowb = (lane >> 4) * 4;
    const size_t kofs = (size_t)(blockIdx.x & 7) * 4096;
    #pragma unroll
    for (int ni = 0; ni < 4; ++ni)
        #pragma unroll
        for (int r = 0; r < 4; ++r)
            qm8[(kofs + m0 + w * 16 + rowb + r) * 64 + ni * 16 + fr] = acc[ni][r];
}

// ---------------------------------------------------------------------------
// K1b: sum 8 partials -> LN -> GELU -> score. Wave = 1 row, 1024 blocks.
// ---------------------------------------------------------------------------
__global__ __launch_bounds__(256) void k_score_tail(
    const float* __restrict__ qm8, const float* __restrict__ lng,
    const float* __restrict__ lnb, const float* __restrict__ w1f,
    const float* __restrict__ b1f, const float* __restrict__ w2f,
    const float* __restrict__ b2f, float* __restrict__ scores) {
    const int w = threadIdx.x >> 6, lane = threadIdx.x & 63;
    const int r = blockIdx.x * 4 + w;
    __shared__ float Hs[4][64];
    __shared__ float hh[4][16];

    float qm = 0.f;
    #pragma unroll
    for (int ks = 0; ks < 8; ++ks)
        qm += qm8[((size_t)ks * 4096 + r) * 64 + lane];
    float s = qm;
    #pragma unroll
    for (int off = 32; off > 0; off >>= 1) s += __shfl_xor(s, off);
    float mu = s * (1.f / 64.f);
    float dx = qm - mu;
    float v2 = dx * dx;
    #pragma unroll
    for (int off = 32; off > 0; off >>= 1) v2 += __shfl_xor(v2, off);
    float var = v2 * (1.f / 64.f);
    float H = dx * (1.0f / sqrtf(var + 1e-5f)) * lng[lane] + lnb[lane];
    Hs[w][lane] = H;
    if (lane < 16) {
        float a = b1f[lane];
        #pragma unroll
        for (int d = 0; d < 64; ++d) a += Hs[w][d] * w1f[lane * 64 + d];
        hh[w][lane] = 0.5f * a * (1.0f + erff(a * 0.70710678118654752f));
    }
    if (lane == 0) {
        float sc = b2f[0];
        #pragma unroll
        for (int p = 0; p < 16; ++p) sc += hh[w][p] * w2f[p];
        scores[r] = sc;
    }
}

// ---------------------------------------------------------------------------
// K2: top-256 radix select; emits full gate, ascending index list, compact gate.
// ---------------------------------------------------------------------------
__global__ __launch_bounds__(256) void k_topk(const float* __restrict__ scores,
                                              float* __restrict__ gate,
                                              int* __restrict__ idx,
                                              float* __restrict__ gsel) {
    const int w = threadIdx.x >> 6, lane = threadIdx.x & 63;   // w = batch
    const float* sc = scores + w * 1024;
    float s[16];
    uint32_t key[16];
    #pragma unroll
    for (int i = 0; i < 16; ++i) {
        s[i] = sc[lane * 16 + i];
        uint32_t u = __float_as_uint(s[i]);
        key[i] = (u >> 31) ? ~u : (u | 0x80000000u);
    }
    uint32_t prefix = 0;
    for (int bit = 31; bit >= 0; --bit) {
        uint32_t cand = prefix | (1u << bit);
        int c = 0;
        #pragma unroll
        for (int i = 0; i < 16; ++i) c += (key[i] >= cand);
        #pragma unroll
        for (int off = 1; off < 64; off <<= 1) c += __shfl_xor(c, off);
        if (c >= 256) prefix = cand;
    }
    int cg = 0, eq = 0;
    #pragma unroll
    for (int i = 0; i < 16; ++i) { cg += (key[i] > prefix); eq += (key[i] == prefix); }
    #pragma unroll
    for (int off = 1; off < 64; off <<= 1) cg += __shfl_xor(cg, off);
    const int quota = 256 - cg;
    int xs = eq;
    #pragma unroll
    for (int off = 1; off < 64; off <<= 1) {
        int y = __shfl_up(xs, off);
        if (lane >= off) xs += y;
    }
    int run = xs - eq;
    bool selv[16];
    int cnt = 0;
    #pragma unroll
    for (int i = 0; i < 16; ++i) {
        bool sel = key[i] > prefix;
        if (key[i] == prefix) { sel = (run < quota); run++; }
        selv[i] = sel;
        cnt += sel ? 1 : 0;
        gate[w * 1024 + lane * 16 + i] = sel ? 1.0f / (1.0f + expf(-s[i])) : 0.0f;
    }
    int xc = cnt;
    #pragma unroll
    for (int off = 1; off < 64; off <<= 1) {
        int y = __shfl_up(xc, off);
        if (lane >= off) xc += y;
    }
    int pos = xc - cnt;
    #pragma unroll
    for (int i = 0; i < 16; ++i) {
        if (selv[i]) {
            idx[w * 256 + pos]  = lane * 16 + i;
            gsel[w * 256 + pos] = 1.0f / (1.0f + expf(-s[i]));
            pos++;
        }
    }
}

// ---------------------------------------------------------------------------
// K3: sparse QKV on the 1024 gathered rows, cols [0,3072) over wq|wk|wv.
// Retiled 64m x 128n for occupancy: grid 384 GEMM (16 m x 24 n) + 16 meanV.
// q -> qsel[compact][1024], k -> ksel[bh][256][64], v -> VselT[bh][64][256].
// ---------------------------------------------------------------------------
__global__ __launch_bounds__(256) void k_qkv_sel(
    const bf16* __restrict__ xb, const bf16* __restrict__ wqb,
    const int* __restrict__ idx, bf16* __restrict__ qsel,
    bf16* __restrict__ ksel, bf16* __restrict__ VselT,
    const float* __restrict__ xsum, float* __restrict__ meanVbuf) {
    __shared__ bf16 As[64 * 32];
    __shared__ bf16 Bs[128 * 32];
    __shared__ float xsS[1024];
    const int t = threadIdx.x;

    if (blockIdx.x >= 384) {
        const int j = blockIdx.x - 384, b = j >> 2, kq = j & 3;
        for (int k = t; k < 1024; k += 256) xsS[k] = xsum[b * 1024 + k];
        __syncthreads();
        const int k2 = kq * 256 + t;
        const bf16* wr = wqb + (size_t)(2048 + k2) * 1024;
        float s = 0.f;
        for (int k = 0; k < 1024; k += 8) {
            bf16x8 v = *(const bf16x8*)(wr + k);
            #pragma unroll
            for (int jj = 0; jj < 8; ++jj) s += (float)v[jj] * xsS[k + jj];
        }
        meanVbuf[b * 1024 + k2] = s * (1.f / 1024.f);
        return;
    }

    const int lane = t & 63;
    const int w = t >> 6;
    const int srow = t >> 2;           // 0..63
    const int scol = (t & 3) * 8;
    const int fr = lane & 15;
    const int kc = (lane >> 4) * 8;

    const int bid = blockIdx.x;
    const int n0 = (bid % 24) * 128;   // [0,3072) over wq|wk|wv
    const int m0 = (bid / 24) * 64;    // compact rows [0,1024)
    const bf16* Bsrc = wqb + (size_t)n0 * 1024;
    const int mg1 = m0 + srow;
    const int tok1 = idx[(mg1 >> 8) * 256 + (mg1 & 255)];
    const size_t abase1 = ((size_t)(mg1 >> 8) * 1024 + tok1) * 1024;

    floatx4 zero4 = {0.f, 0.f, 0.f, 0.f};
    floatx4 acc[4][2];
    #pragma unroll
    for (int i = 0; i < 4; ++i)
        #pragma unroll
        for (int j = 0; j < 2; ++j) acc[i][j] = zero4;

    for (int k0 = 0; k0 < 1024; k0 += 32) {
        __syncthreads();
        cp16(As + t * 8,        xb + abase1 + k0 + scol);
        cp16(Bs + t * 8,        Bsrc + (size_t)srow * 1024 + k0 + scol);
        cp16(Bs + t * 8 + 2048, Bsrc + (size_t)(srow + 64) * 1024 + k0 + scol);
        __syncthreads();
        bf16x8 a[4], b[2];
        #pragma unroll
        for (int mi = 0; mi < 4; ++mi)
            a[mi] = *(const bf16x8*)&As[(mi * 16 + fr) * 32 + kc];
        #pragma unroll
        for (int ni = 0; ni < 2; ++ni)
            b[ni] = *(const bf16x8*)&Bs[(w * 32 + ni * 16 + fr) * 32 + kc];
        #pragma unroll
        for (int mi = 0; mi < 4; ++mi)
            #pragma unroll
            for (int ni = 0; ni < 2; ++ni)
                acc[mi][ni] = MFMA16(a[mi], b[ni], acc[mi][ni]);
    }

    const int rowb = (lane >> 4) * 4;
    #pragma unroll
    for (int ni = 0; ni < 2; ++ni) {
        const int n_base = n0 + w * 32 + ni * 16;
        const int region = n_base >> 10;   // 0=q 1=k 2=v
        const int nn = n_base & 1023;
        const int h = nn >> 6;
        const int dd = (nn & 63) + fr;
        if (region < 2) {
            #pragma unroll
            for (int mi = 0; mi < 4; ++mi)
                #pragma unroll
                for (int r = 0; r < 4; ++r) {
                    const int mg = m0 + mi * 16 + rowb + r;  // compact row
                    const bf16 v = (bf16)acc[mi][ni][r];
                    if (region == 0) {
                        qsel[(size_t)mg * 1024 + h * 64 + dd] = v;
                    } else {
                        const int b = mg >> 8, s = mg & 255;
                        ksel[(((size_t)(b * 16 + h)) * 256 + s) * 64 + dd] = v;
                    }
                }
        } else {
            #pragma unroll
            for (int mi = 0; mi < 4; ++mi) {
                const int mgb = m0 + mi * 16 + rowb;   // multiple of 4
                const int b = mgb >> 8, s0 = mgb & 255;
                union { bf16 h4[4]; uint2 u; } pk;
                #pragma unroll
                for (int r = 0; r < 4; ++r) pk.h4[r] = (bf16)acc[mi][ni][r];
                *(uint2*)&VselT[(((size_t)(b * 16 + h)) * 64 + dd) * 256 + s0] = pk.u;
            }
        }
    }
}

// ---------------------------------------------------------------------------
// K4: gated attention (256 blocks, bh x qt) with fused in-block SumVuns
//     (= meanVbuf*1024 - sum_s VselT), + 16 ubase blocks (meanV @ wo + b_out).
// ---------------------------------------------------------------------------
__global__ __launch_bounds__(256) void k_attn(
    bf16* __restrict__ qsel, const bf16* __restrict__ Ksel,
    const bf16* __restrict__ VselT, const float* __restrict__ gsel,
    const float* __restrict__ meanVbuf, const bf16* __restrict__ wob,
    const float* __restrict__ b_out, float* __restrict__ ubase) {
    __shared__ bf16 Qs[64 * 72];
    __shared__ bf16 Ks[64 * 72];
    __shared__ bf16 Vs[64 * 72];
    __shared__ bf16 Ps[4][16 * 72];
    __shared__ float redS[4][64];
    __shared__ float SumV[64];
    __shared__ float mvS[1024];
    const int t = threadIdx.x;

    if (blockIdx.x >= 256) {
        const int j = blockIdx.x - 256, bb = j >> 2, nq = j & 3;
        for (int k = t; k < 1024; k += 256) mvS[k] = meanVbuf[bb * 1024 + k];
        __syncthreads();
        const int n = nq * 256 + t;
        const bf16* wr = wob + (size_t)n * 1024;
        float s = b_out[n];
        for (int k = 0; k < 1024; k += 8) {
            bf16x8 v = *(const bf16x8*)(wr + k);
            #pragma unroll
            for (int jj = 0; jj < 8; ++jj) s += (float)v[jj] * mvS[k + jj];
        }
        ubase[bb * 1024 + n] = s;
        return;
    }

    const int bh = blockIdx.x >> 2;   // 0..63
    const int qt = blockIdx.x & 3;    // 0..3
    const int b = bh >> 4, h = bh & 15;
    const int w = t >> 6, lane = t & 63;
    const int m0 = qt * 64;      // compact row within batch
    const bf16* kb = Ksel + (size_t)bh * 16384;
    const bf16* vb = VselT + (size_t)bh * 16384;

    #pragma unroll
    for (int c = 0; c < 2; ++c) {
        int idx2 = t + 256 * c, row = idx2 >> 3, c8 = (idx2 & 7) * 8;
        *(uint4*)&Qs[row * 72 + c8] =
            *(const uint4*)&qsel[(size_t)(b * 256 + m0 + row) * 1024 + h * 64 + c8];
    }
    // sSel partials: thread (d = t&63, part = t>>6) sums 64 s of VselT[bh][d][:]
    {
        const int dd_ = t & 63, pp_ = t >> 6;
        const bf16* vr = vb + (size_t)dd_ * 256 + pp_ * 64;
        float ss = 0.f;
        #pragma unroll
        for (int k = 0; k < 64; k += 8) {
            bf16x8 v = *(const bf16x8*)(vr + k);
            #pragma unroll
            for (int jj = 0; jj < 8; ++jj) ss += (float)v[jj];
        }
        redS[pp_][dd_] = ss;
    }
    const int fr = lane & 15;
    const int kq = lane >> 4;
    const int rowb = kq * 4;
    __syncthreads();
    if (t < 64)
        SumV[t] = meanVbuf[b * 1024 + h * 64 + t] * 1024.f -
                  (redS[0][t] + redS[1][t] + redS[2][t] + redS[3][t]);
    bf16x8 aq[2];
    aq[0] = *(const bf16x8*)&Qs[(w * 16 + fr) * 72 + kq * 8];
    aq[1] = *(const bf16x8*)&Qs[(w * 16 + fr) * 72 + 32 + kq * 8];

    float gq[4];
    #pragma unroll
    for (int r = 0; r < 4; ++r)
        gq[r] = gsel[b * 256 + m0 + w * 16 + rowb + r] * SCALE_;

    float mrow[4] = {0.f, 0.f, 0.f, 0.f};
    float lrow[4] = {0.f, 0.f, 0.f, 0.f};
    floatx4 zero4 = {0.f, 0.f, 0.f, 0.f};
    floatx4 Of[4] = {zero4, zero4, zero4, zero4};

    for (int jt = 0; jt < 4; ++jt) {
        const int j0 = jt * 64;
        __syncthreads();
        #pragma unroll
        for (int c = 0; c < 2; ++c) {
            int idx2 = t + 256 * c, row = idx2 >> 3, c8 = (idx2 & 7) * 8;
            *(uint4*)&Ks[row * 72 + c8] = *(const uint4*)&kb[(size_t)(j0 + row) * 64 + c8];
            *(uint4*)&Vs[row * 72 + c8] = *(const uint4*)&vb[(size_t)row * 256 + j0 + c8];
        }
        __syncthreads();

        floatx4 S[4] = {zero4, zero4, zero4, zero4};
        #pragma unroll
        for (int ks = 0; ks < 2; ++ks) {
            #pragma unroll
            for (int ni = 0; ni < 4; ++ni) {
                bf16x8 bfr = *(const bf16x8*)&Ks[(ni * 16 + fr) * 72 + ks * 32 + kq * 8];
                S[ni] = MFMA16(aq[ks], bfr, S[ni]);
            }
        }
        float gk[4];
        #pragma unroll
        for (int ni = 0; ni < 4; ++ni) gk[ni] = gsel[b * 256 + j0 + ni * 16 + fr];

        float p[4][4], rmax[4] = {0.f, 0.f, 0.f, 0.f};
        #pragma unroll
        for (int ni = 0; ni < 4; ++ni)
            #pragma unroll
            for (int r = 0; r < 4; ++r) {
                float sv = S[ni][r] * (gq[r] * gk[ni]);
                p[ni][r] = sv;
                rmax[r] = fmaxf(rmax[r], sv);
            }
        #pragma unroll
        for (int r = 0; r < 4; ++r) {
            #pragma unroll
            for (int off = 1; off < 16; off <<= 1)
                rmax[r] = fmaxf(rmax[r], __shfl_xor(rmax[r], off));
        }
        float alpha[4], rsum[4] = {0.f, 0.f, 0.f, 0.f};
        #pragma unroll
        for (int r = 0; r < 4; ++r) {
            float mn = fmaxf(mrow[r], rmax[r]);
            alpha[r] = __expf(mrow[r] - mn);
            mrow[r] = mn;
        }
        #pragma unroll
        for (int ni = 0; ni < 4; ++ni)
            #pragma unroll
            for (int r = 0; r < 4; ++r) {
                float pv = __expf(p[ni][r] - mrow[r]);
                p[ni][r] = pv;
                rsum[r] += pv;
            }
        #pragma unroll
        for (int r = 0; r < 4; ++r) {
            #pragma unroll
            for (int off = 1; off < 16; off <<= 1) rsum[r] += __shfl_xor(rsum[r], off);
            lrow[r] = lrow[r] * alpha[r] + rsum[r];
        }
        #pragma unroll
        for (int nd = 0; nd < 4; ++nd)
            #pragma unroll
            for (int r = 0; r < 4; ++r) Of[nd][r] *= alpha[r];

        #pragma unroll
        for (int ni = 0; ni < 4; ++ni)
            #pragma unroll
            for (int r = 0; r < 4; ++r)
                Ps[w][(rowb + r) * 72 + ni * 16 + fr] = (bf16)p[ni][r];

        #pragma unroll
        for (int ks = 0; ks < 2; ++ks) {
            bf16x8 ap = *(const bf16x8*)&Ps[w][fr * 72 + ks * 32 + kq * 8];
            #pragma unroll
            for (int nd = 0; nd < 4; ++nd) {
                bf16x8 bv = *(const bf16x8*)&Vs[(nd * 16 + fr) * 72 + ks * 32 + kq * 8];
                Of[nd] = MFMA16(ap, bv, Of[nd]);
            }
        }
    }

    #pragma unroll
    for (int nd = 0; nd < 4; ++nd)
        #pragma unroll
        for (int r = 0; r < 4; ++r) {
            float em = __expf(-mrow[r]);
            float num = Of[nd][r] + em * SumV[nd * 16 + fr];
            float den = lrow[r] + 768.0f * em;
            qsel[(size_t)(b * 256 + m0 + w * 16 + rowb + r) * 1024 +
                 h * 64 + nd * 16 + fr] = (bf16)(num / den);
        }
}

// ---------------------------------------------------------------------------
// K5a: out GEMM partials. 64m x 128n tiles, split-K x2.
// grid 256 = (16 m x 8 n) x 2 ks. outP[ks][1024][1024] fp32 (xb slot, dead).
// ---------------------------------------------------------------------------
__global__ __launch_bounds__(256) void k_out_gemm(
    const bf16* __restrict__ A, const bf16* __restrict__ wob,
    float* __restrict__ outP) {
    __shared__ bf16 As[64 * 32];
    __shared__ bf16 Bs[128 * 32];
    const int t = threadIdx.x;
    const int lane = t & 63;
    const int w = t >> 6;
    const int srow = t >> 2;
    const int scol = (t & 3) * 8;
    const int fr = lane & 15;
    const int kc = (lane >> 4) * 8;

    const int ks = blockIdx.x >> 7;          // 0..1
    const int rem = blockIdx.x & 127;
    const int m0 = (rem >> 3) * 64;
    const int n0 = (rem & 7) * 128;
    const int kbase = ks * 512;
    const bf16* Bsrc = wob + (size_t)n0 * 1024;

    floatx4 zero4 = {0.f, 0.f, 0.f, 0.f};
    floatx4 acc[4][2];
    #pragma unroll
    for (int i = 0; i < 4; ++i)
        #pragma unroll
        for (int j = 0; j < 2; ++j) acc[i][j] = zero4;

    for (int k0 = kbase; k0 < kbase + 512; k0 += 32) {
        __syncthreads();
        cp16(As + t * 8,        A + (size_t)(m0 + srow) * 1024 + k0 + scol);
        cp16(Bs + t * 8,        Bsrc + (size_t)srow * 1024 + k0 + scol);
        cp16(Bs + t * 8 + 2048, Bsrc + (size_t)(srow + 64) * 1024 + k0 + scol);
        __syncthreads();
        bf16x8 a[4], b[2];
        #pragma unroll
        for (int mi = 0; mi < 4; ++mi)
            a[mi] = *(const bf16x8*)&As[(mi * 16 + fr) * 32 + kc];
        #pragma unroll
        for (int ni = 0; ni < 2; ++ni)
            b[ni] = *(const bf16x8*)&Bs[(w * 32 + ni * 16 + fr) * 32 + kc];
        #pragma unroll
        for (int mi = 0; mi < 4; ++mi)
            #pragma unroll
            for (int ni = 0; ni < 2; ++ni)
                acc[mi][ni] = MFMA16(a[mi], b[ni], acc[mi][ni]);
    }

    const int rowb = (lane >> 4) * 4;
    float* dst = outP + (size_t)ks * 1048576;
    #pragma unroll
    for (int ni = 0; ni < 2; ++ni) {
        const int ng = n0 + w * 32 + ni * 16 + fr;
        #pragma unroll
        for (int mi = 0; mi < 4; ++mi)
            #pragma unroll
            for (int r = 0; r < 4; ++r) {
                const int mg = m0 + mi * 16 + rowb + r;
                dst[(size_t)mg * 1024 + ng] = acc[mi][ni][r];
            }
    }
}

// ---------------------------------------------------------------------------
// K5b: reduce 2 partials + bias, scatter to out; + fill blocks.
// blocks [0,1024): compact row reduce+scatter. [1024,2048): fill 4 tokens.
// ---------------------------------------------------------------------------
__global__ __launch_bounds__(256) void k_out_red(
    const float* __restrict__ outP, const float* __restrict__ b_out,
    const int* __restrict__ idx, const float* __restrict__ ubase,
    const float* __restrict__ gate, float* __restrict__ out) {
    const int t = threadIdx.x, gb = blockIdx.x;
    if (gb < 1024) {
        const int mg = gb;
        const int c = t * 4;
        float4 v0 = *(const float4*)(outP + (size_t)mg * 1024 + c);
        float4 v1 = *(const float4*)(outP + 1048576 + (size_t)mg * 1024 + c);
        float4 bb = *(const float4*)(b_out + c);
        float4 r;
        r.x = v0.x + v1.x + bb.x;
        r.y = v0.y + v1.y + bb.y;
        r.z = v0.z + v1.z + bb.z;
        r.w = v0.w + v1.w + bb.w;
        const int b = mg >> 8, s = mg & 255;
        const int tok = idx[b * 256 + s];
        *(float4*)(out + ((size_t)b * 1024 + tok) * 1024 + c) = r;
    } else {
        const int fb = gb - 1024;          // 0..1023
        const int c = t * 4;
        #pragma unroll
        for (int r = 0; r < 4; ++r) {
            const int tokg = fb * 4 + r;
            if (gate[tokg] > 0.f) continue;
            const int b = tokg >> 10;
            *(float4*)(out + (size_t)tokg * 1024 + c) =
                *(const float4*)(ubase + b * 1024 + c);
        }
    }
}

// ---------------------------------------------------------------------------
extern "C" void kernel_launch(void* const* d_in, const int* in_sizes, int n_in,
                              void* d_out, int out_size, void* d_ws, size_t ws_size,
                              hipStream_t stream) {
    const float* x     = (const float*)d_in[0];
    const float* w_qkv = (const float*)d_in[1];
    const float* w_out = (const float*)d_in[2];
    const float* b_out = (const float*)d_in[3];
    const float* ln_g  = (const float*)d_in[4];
    const float* ln_b  = (const float*)d_in[5];
    const float* w1    = (const float*)d_in[6];
    const float* b1    = (const float*)d_in[7];
    const float* w2    = (const float*)d_in[8];
    const float* b2    = (const float*)d_in[9];
    float* out = (float*)d_out;

    char* ws = (char*)d_ws;
    bf16*  qsel  = (bf16*)(ws);                  // 4 MB slot (1024x1024 bf16 used)
    bf16*  ksel  = (bf16*)(ws + 4194304);        // 2 MB
    bf16*  VselT = (bf16*)(ws + 6291456);        // 2 MB
    float* qm8   = (float*)(ws);                 // 8 MB, aliases qsel|ksel|VselT
                                                 // (consumed by k_score_tail BEFORE
                                                 //  k_qkv_sel writes those slots)
    float* xsum  = (float*)(ws + 8388608);       // 16 KB (4 x 1024 fp32)
    bf16*  xb    = (bf16*)(ws + 16777216);       // 8 MB
    float* outP  = (float*)(ws + 16777216);      // 8 MB, aliases xb (xb dead by
                                                 //  the time k_out_gemm runs)
    bf16*  wqb   = (bf16*)(ws + 25165824);       // 6 MB
    bf16*  wob   = (bf16*)(ws + 31457280);       // 2 MB
    int*   idx      = (int*)(ws + 33554432);     // 4 KB
    float* gsel     = (float*)(ws + 33558528);   // 4 KB
    float* scores   = (float*)(ws + 33562624);   // 16 KB
    float* gate     = (float*)(ws + 33579008);   // 16 KB
    float* meanVbuf = (float*)(ws + 33595392);   // 16 KB
    float* ubase    = (float*)(ws + 33611776);   // 16 KB
    bf16*  whl      = (bf16*)(ws + 33685504);    // 256 KB (wh|wl rows)
    bf16*  xlbuf    = (bf16*)(ws + 35651584);    // 8 MB (x bf16 residual)

    k_cvt_prep<<<4416, 256, 0, stream>>>(x, w_qkv, w_out, xb, xlbuf, wqb, wob, whl, xsum);
    k_score_gemm<<<512, 256, 0, stream>>>(xb, xlbuf, whl, qm8);
    k_score_tail<<<1024, 256, 0, stream>>>(qm8, ln_g, ln_b, w1, b1, w2, b2, scores);
    k_topk<<<1, 256, 0, stream>>>(scores, gate, idx, gsel);
    k_qkv_sel<<<400, 256, 0, stream>>>(xb, wqb, idx, qsel, ksel, VselT, xsum, meanVbuf);
    k_attn<<<272, 256, 0, stream>>>(qsel, ksel, VselT, gsel, meanVbuf, wob, b_out, ubase);
    k_out_gemm<<<256, 256, 0, stream>>>(qsel, wob, outP);
    k_out_red<<<2048, 256, 0, stream>>>(outP, b_out, idx, ubase, gate, out);
}